// Round 7
// baseline (211.352 us; speedup 1.0000x reference)
//
#include <hip/hip_runtime.h>

typedef unsigned short ushort_t;
typedef __bf16 bf16x8 __attribute__((ext_vector_type(8)));
typedef float  f32x4  __attribute__((ext_vector_type(4)));

#define MFMA16(a,b,c) __builtin_amdgcn_mfma_f32_16x16x32_bf16((a),(b),(c),0,0,0)

__device__ __forceinline__ ushort_t f2bf(float f) {
    union { float f; unsigned u; } x; x.f = f;
    unsigned r = (x.u + 0x7fffu + ((x.u >> 16) & 1u)) >> 16;
    return (ushort_t)r;
}

__device__ __forceinline__ void gload16(const ushort_t* g, char* l) {
    __builtin_amdgcn_global_load_lds(
        (const __attribute__((address_space(1))) unsigned*)g,
        (__attribute__((address_space(3))) unsigned*)l, 16, 0, 0);
}

// ---------------- all casts in one launch ----------------
// 2M float4 units: [0,1M) = x -> xbf; [1M,2M) = Wq|Wk|Wv|Wo -> wqkv / wob.
__global__ void cast_all(const float* __restrict__ x,
                         const float* __restrict__ Wq, const float* __restrict__ Wk,
                         const float* __restrict__ Wv, const float* __restrict__ Wo,
                         ushort_t* __restrict__ xbf, ushort_t* __restrict__ wqkv,
                         ushort_t* __restrict__ wob) {
    int i = blockIdx.x * 256 + threadIdx.x;
    float4 v;
    if (i < 1048576) {
        v = ((const float4*)x)[i];
        ushort4 o;
        o.x = f2bf(v.x); o.y = f2bf(v.y); o.z = f2bf(v.z); o.w = f2bf(v.w);
        ((ushort4*)xbf)[i] = o;
    } else {
        int j = i - 1048576;
        int r = j >> 18, jj = j & 0x3ffff;
        const float* src = (r == 0) ? Wq : (r == 1) ? Wk : (r == 2) ? Wv : Wo;
        v = ((const float4*)src)[jj];
        ushort4 o;
        o.x = f2bf(v.x); o.y = f2bf(v.y); o.z = f2bf(v.z); o.w = f2bf(v.w);
        if (r < 3) ((ushort4*)wqkv)[(size_t)r*262144 + jj] = o;
        else       ((ushort4*)wob)[jj] = o;
    }
}

// ---------------- GEMM: C[m,n] = sum_k A[m,k]*W[n,k] (+bias) ----------------
// 128x128 tile, BK=64, 256 thr (4 waves 2x2). global_load_lds(16B) staging:
// linear LDS dest + XOR-preswizzled global source + XOR-swizzled ds_read.
// MODE 0: NW=3072 QKV fused; MODE 1: NW=1024 output proj, fp32 out.
template<int MODE>
__global__ void gemm_bt(const ushort_t* __restrict__ A,
                        const ushort_t* __restrict__ Bw,
                        const float* __restrict__ b0, const float* __restrict__ b1,
                        const float* __restrict__ b2,
                        void* __restrict__ C0, void* __restrict__ C1,
                        void* __restrict__ C2, void* __restrict__ C3,
                        void* __restrict__ C4)
{
    __shared__ __align__(16) char lds[32768];
    char* As = lds;
    char* Bs = lds + 16384;
    const int tid  = threadIdx.x;
    const int lane = tid & 63;
    const int wid  = tid >> 6;
    const int wrow = wid >> 1;
    const int wcol = wid & 1;
    const int m0 = blockIdx.x * 128;
    const int n0 = blockIdx.y * 128;

    f32x4 acc[4][4] = {};

    #define STAGE(kb)                                                          \
        _Pragma("unroll")                                                      \
        for (int k = 0; k < 4; ++k) {                                          \
            int idx = k*256 + tid;                                             \
            int row = idx >> 3, s = idx & 7;                                   \
            int sc = s ^ (row & 7);                                            \
            gload16(A  + (size_t)(m0+row)*1024 + (kb) + sc*8, As + idx*16);    \
            gload16(Bw + (size_t)(n0+row)*1024 + (kb) + sc*8, Bs + idx*16);    \
        }

    STAGE(0)
    for (int kt = 0; kt < 16; ++kt) {
        __syncthreads();
        #pragma unroll
        for (int ks = 0; ks < 2; ++ks) {
            bf16x8 af[4], bfr[4];
            #pragma unroll
            for (int i = 0; i < 4; ++i) {
                int row = wrow*64 + i*16 + (lane & 15);
                int sl  = ks*4 + (lane >> 4);
                af[i] = *(const bf16x8*)(As + row*128 + ((sl ^ (row & 7)) << 4));
            }
            #pragma unroll
            for (int j = 0; j < 4; ++j) {
                int row = wcol*64 + j*16 + (lane & 15);
                int sl  = ks*4 + (lane >> 4);
                bfr[j] = *(const bf16x8*)(Bs + row*128 + ((sl ^ (row & 7)) << 4));
            }
            #pragma unroll
            for (int i = 0; i < 4; ++i)
                #pragma unroll
                for (int j = 0; j < 4; ++j)
                    acc[i][j] = MFMA16(af[i], bfr[j], acc[i][j]);
        }
        __syncthreads();
        if (kt < 15) STAGE((kt+1)*64)
    }
    #undef STAGE

    #pragma unroll
    for (int i = 0; i < 4; ++i) {
        #pragma unroll
        for (int j = 0; j < 4; ++j) {
            #pragma unroll
            for (int q = 0; q < 4; ++q) {
                int gm = m0 + wrow*64 + i*16 + (lane >> 4)*4 + q;
                int gn = n0 + wcol*64 + j*16 + (lane & 15);
                if (MODE == 1) {
                    ((float*)C0)[(size_t)gm*1024 + gn] = acc[i][j][q] + b0[gn];
                } else {
                    int reg = gn >> 10, nn = gn & 1023;
                    float bias = ((reg == 0) ? b0 : (reg == 1) ? b1 : b2)[nn];
                    float v = acc[i][j][q] + bias;
                    int b = gm >> 11, s = gm & 2047;
                    int h = nn >> 6,  dk = nn & 63;
                    int hh = b*16 + h;
                    ushort_t bv = f2bf(v);
                    if (reg == 0) {
                        ((ushort_t*)C0)[((size_t)hh*2048 + s)*64 + dk] = bv;           // Qb
                    } else if (reg == 1) {
                        ((ushort_t*)C1)[((size_t)hh*2048 + s)*64 + dk] = bv;           // Kn
                        ((ushort_t*)C2)[(((size_t)hh*4 + (s & 3))*512 + (s >> 2))*64 + dk] = bv; // Kss
                    } else {
                        ((ushort_t*)C3)[((size_t)hh*64 + dk)*2048 + s] = bv;           // Vtn
                        ((ushort_t*)C4)[(((size_t)hh*4 + (s & 3))*64 + dk)*512 + (s >> 2)] = bv; // Vts
                    }
                }
            }
        }
    }
}

// ---------------- sparse flash attention v4: fixed-offset softmax ----------------
// p = exp(s - 16): no per-row max (safe: fp32 exp overflows only at s>104,
// s = q.k/8 is ~N(0,1); e^{m-16} factor cancels in p/sum(p)), no rescale, and
// the row-sum reduction is deferred to the epilogue (tsum per-lane). Masked
// entries: sv=-1e30 -> exp -> 0. This removes ALL per-iteration shfl chains.
// Grid 1024 XCD-swizzled; wave r owns rows row%4==r of its 64-row block.
__global__ void sparse_attn4(const ushort_t* __restrict__ Qg,
                             const ushort_t* __restrict__ Kn,
                             const ushort_t* __restrict__ Kss,
                             const ushort_t* __restrict__ Vtn,
                             const ushort_t* __restrict__ Vts,
                             ushort_t* __restrict__ attn)
{
    __shared__ __align__(16) char Ps[8192];
    const int tid  = threadIdx.x;
    const int lane = tid & 63;
    const int r    = tid >> 6;
    const int l15  = lane & 15;
    const int lhi  = lane >> 4;
    const int id2  = (blockIdx.x & 7)*128 + (blockIdx.x >> 3);
    const int bh   = id2 >> 5;
    const int rb   = id2 & 31;
    char* Pw = Ps + r*2048;

    bf16x8 aq[2];
    {
        const ushort_t* qp = Qg + ((size_t)bh*2048 + rb*64 + r + 4*l15)*64 + lhi*8;
        aq[0] = *(const bf16x8*)(qp);
        aq[1] = *(const bf16x8*)(qp + 32);
    }

    float tsum[4] = {0.f, 0.f, 0.f, 0.f};
    f32x4 oacc[4] = {};

    // ---- Pass 1: 512 strided columns, unmasked, 8 chunks ----
    const ushort_t* Kst = Kss + ((size_t)bh*4 + r)*512*64;
    const ushort_t* Vst = Vts + ((size_t)bh*4 + r)*64*512;

    bf16x8 kc[8];
    #pragma unroll
    for (int ks = 0; ks < 2; ++ks)
        #pragma unroll
        for (int n = 0; n < 4; ++n)
            kc[ks*4+n] = *(const bf16x8*)(Kst + (size_t)(n*16 + l15)*64 + ks*32 + lhi*8);

    for (int c = 0; c < 8; ++c) {
        const int t0 = c*64;
        bf16x8 vc[8];
        #pragma unroll
        for (int ks = 0; ks < 2; ++ks)
            #pragma unroll
            for (int d = 0; d < 4; ++d)
                vc[ks*4+d] = *(const bf16x8*)(Vst + (size_t)(d*16 + l15)*512 + t0 + ks*32 + lhi*8);
        f32x4 sacc[4] = {};
        #pragma unroll
        for (int ks = 0; ks < 2; ++ks)
            #pragma unroll
            for (int n = 0; n < 4; ++n)
                sacc[n] = MFMA16(aq[ks], kc[ks*4+n], sacc[n]);
        bf16x8 kn2[8];
        if (c < 7) {
            #pragma unroll
            for (int ks = 0; ks < 2; ++ks)
                #pragma unroll
                for (int n = 0; n < 4; ++n)
                    kn2[ks*4+n] = *(const bf16x8*)(Kst + (size_t)(t0 + 64 + n*16 + l15)*64 + ks*32 + lhi*8);
        }
        // p = exp(s/8 - 16); accumulate per-lane sum; stash bf16 P in LDS
        #pragma unroll
        for (int n = 0; n < 4; ++n) {
            int colb = (n*16 + l15) * 2;
            #pragma unroll
            for (int q = 0; q < 4; ++q) {
                float p = __expf(sacc[n][q]*0.125f - 16.f);
                tsum[q] += p;
                int rowp = lhi*4 + q;
                *(__bf16*)(Pw + rowp*128 + (colb ^ ((rowp & 7) << 4))) = (__bf16)p;
            }
        }
        #pragma unroll
        for (int ks = 0; ks < 2; ++ks) {
            int sl = ks*4 + lhi;
            bf16x8 pf = *(const bf16x8*)(Pw + l15*128 + ((sl ^ (l15 & 7)) << 4));
            #pragma unroll
            for (int d = 0; d < 4; ++d)
                oacc[d] = MFMA16(pf, vc[ks*4+d], oacc[d]);
        }
        if (c < 7) {
            #pragma unroll
            for (int t = 0; t < 8; ++t) kc[t] = kn2[t];
        }
    }

    // ---- Pass 2: local window minus strided ----
    const int bl0 = (rb > 0)  ? rb-1 : 0;
    const int bl1 = (rb < 31) ? rb+1 : 31;
    const bool notstr = ((l15 & 3) != r);
    for (int bl = bl0; bl <= bl1; ++bl) {
        bf16x8 vc[8];
        #pragma unroll
        for (int ks = 0; ks < 2; ++ks)
            #pragma unroll
            for (int d = 0; d < 4; ++d)
                vc[ks*4+d] = *(const bf16x8*)(Vtn + ((size_t)bh*64 + d*16 + l15)*2048 + bl*64 + ks*32 + lhi*8);
        f32x4 sacc[4] = {};
        #pragma unroll
        for (int ks = 0; ks < 2; ++ks) {
            bf16x8 bk[4];
            #pragma unroll
            for (int n = 0; n < 4; ++n)
                bk[n] = *(const bf16x8*)(Kn + ((size_t)bh*2048 + bl*64 + n*16 + l15)*64 + ks*32 + lhi*8);
            #pragma unroll
            for (int n = 0; n < 4; ++n)
                sacc[n] = MFMA16(aq[ks], bk[n], sacc[n]);
        }
        #pragma unroll
        for (int n = 0; n < 4; ++n) {
            int j = bl*64 + n*16 + l15;
            int colb = (n*16 + l15) * 2;
            #pragma unroll
            for (int q = 0; q < 4; ++q) {
                int i = rb*64 + r + 16*lhi + 4*q;
                int d = j - i;
                bool valid = notstr && (d <= 32) && (d >= -32);
                float sv = valid ? sacc[n][q]*0.125f : -1e30f;
                float p = __expf(sv - 16.f);
                tsum[q] += p;
                int rowp = lhi*4 + q;
                *(__bf16*)(Pw + rowp*128 + (colb ^ ((rowp & 7) << 4))) = (__bf16)p;
            }
        }
        #pragma unroll
        for (int ks = 0; ks < 2; ++ks) {
            int sl = ks*4 + lhi;
            bf16x8 pf = *(const bf16x8*)(Pw + l15*128 + ((sl ^ (l15 & 7)) << 4));
            #pragma unroll
            for (int d = 0; d < 4; ++d)
                oacc[d] = MFMA16(pf, vc[ks*4+d], oacc[d]);
        }
    }

    // ---- epilogue: single deferred row-sum reduction + normalize ----
    const int b = bh >> 4, h = bh & 15;
    f32x4 invv;
    #pragma unroll
    for (int q = 0; q < 4; ++q) {
        float t = tsum[q];
        t += __shfl_xor(t, 1);
        t += __shfl_xor(t, 2);
        t += __shfl_xor(t, 4);
        t += __shfl_xor(t, 8);
        invv[q] = 1.f / t;
    }
    #pragma unroll
    for (int d = 0; d < 4; ++d) {
        f32x4 o = oacc[d] * invv;
        #pragma unroll
        for (int q = 0; q < 4; ++q) {
            int srow = rb*64 + r + 16*lhi + 4*q;
            int gr = b*2048 + srow;
            int gc = h*64 + d*16 + l15;
            attn[(size_t)gr*1024 + gc] = f2bf(o[q]);
        }
    }
}

extern "C" void kernel_launch(void* const* d_in, const int* in_sizes, int n_in,
                              void* d_out, int out_size, void* d_ws, size_t ws_size,
                              hipStream_t stream)
{
    const float* x  = (const float*)d_in[0];
    const float* Wq = (const float*)d_in[1];
    const float* bq = (const float*)d_in[2];
    const float* Wk = (const float*)d_in[3];
    const float* bk = (const float*)d_in[4];
    const float* Wv = (const float*)d_in[5];
    const float* bv = (const float*)d_in[6];
    const float* Wo = (const float*)d_in[7];
    const float* bo = (const float*)d_in[8];

    char* ws = (char*)d_ws;
    ushort_t* xbf  = (ushort_t*)(ws);                        // 8 MB
    ushort_t* wqkv = (ushort_t*)(ws + ((size_t)8  << 20));   // 6 MB [3072][1024]
    ushort_t* wob  = (ushort_t*)(ws + ((size_t)14 << 20));   // 2 MB
    ushort_t* Qb   = (ushort_t*)(ws + ((size_t)16 << 20));   // 8 MB [BH,S,Dk]
    ushort_t* Kn   = (ushort_t*)(ws + ((size_t)24 << 20));   // 8 MB [BH,S,Dk]
    ushort_t* Kss  = (ushort_t*)(ws + ((size_t)32 << 20));   // 8 MB [BH,4,512,64]
    ushort_t* Vtn  = (ushort_t*)(ws + ((size_t)40 << 20));   // 8 MB [BH,Dk,S]
    ushort_t* Vts  = (ushort_t*)(ws + ((size_t)48 << 20));   // 8 MB [BH,4,64,512]
    ushort_t* attn = (ushort_t*)(ws + ((size_t)56 << 20));   // 8 MB

    cast_all<<<8192, 256, 0, stream>>>(x, Wq, Wk, Wv, Wo, xbf, wqkv, wob);

    gemm_bt<0><<<dim3(32, 24), 256, 0, stream>>>(xbf, wqkv, bq, bk, bv,
                                                 Qb, Kn, Kss, Vtn, Vts);

    sparse_attn4<<<dim3(1024), 256, 0, stream>>>(Qb, Kn, Kss, Vtn, Vts, attn);

    gemm_bt<1><<<dim3(32, 8), 256, 0, stream>>>(attn, wob, bo, nullptr, nullptr,
                                                d_out, nullptr, nullptr, nullptr, nullptr);
}